// Round 10
// baseline (3514.868 us; speedup 1.0000x reference)
//
#include <hip/hip_runtime.h>
#include <cstdint>
#include <cstddef>

// GroupPointNet: FPS -> kNN(20) -> gf=(dp,grouped) -> 3x(conv1x1+lrelu+BN) -> max_k
// B=4, N=8192, M=2048, K=20, C=64. All f32.
// R10: fps 256thr x 32pts LDS-streamed (j-loop issue constant, per-wave fixed cost paid
// once, no big register arrays); convB+stats2 fused (LDS transpose); stats3+maxpool
// fused (single u2t pass, mx/mn to ws) + tiny apply. 5 launches.

#define B_ 4
#define N_ 8192
#define M_ 2048
#define K_ 20
#define BMK (B_*M_*K_)   // 163840
#define EPS_ 1e-5f

typedef unsigned long long ull;

// ---------- helpers ----------
__device__ __forceinline__ ull packkey(float d, int idx) {
  unsigned int bb = __float_as_uint(d);
  bb ^= (bb & 0x80000000u) ? 0xFFFFFFFFu : 0x80000000u;  // order-preserving map
  return ((ull)bb << 32) | (unsigned int)idx;
}
__device__ __forceinline__ float keymaxf(ull k) {
  unsigned int hb = (unsigned int)(k >> 32);
  unsigned int fb = (hb & 0x80000000u) ? (hb ^ 0x80000000u) : ~hb;
  return __uint_as_float(fb);
}
// keys sorted ascending; caller guarantees key < keys[19]
__device__ __forceinline__ void insert20(ull* keys, ull key) {
#pragma unroll
  for (int i = 19; i > 0; --i) {
    ull lo = keys[i-1];
    keys[i] = (key < lo) ? lo : ((key < keys[i]) ? key : keys[i]);
  }
  keys[0] = (key < keys[0]) ? key : keys[0];
}

// ---------- FPS: 1 block/batch, 256 thr x 32 pts from LDS quads, 1 barrier/iter ----------
// key = (dist_bits << 32) | ~idx : max-reduce => argmax with first-index tie-break.
// dist >= 0 so float bits compare as u32. Also zeros the stats accumulators (init fused).
#define DPPSTEP(CTRL) {                                                              \
    unsigned int nhi = (unsigned int)__builtin_amdgcn_update_dpp(                    \
        (int)hi, (int)hi, CTRL, 0xF, 0xF, false);                                    \
    unsigned int nlo = (unsigned int)__builtin_amdgcn_update_dpp(                    \
        (int)lo, (int)lo, CTRL, 0xF, 0xF, false);                                    \
    bool tk = (nhi > hi) | ((nhi == hi) & (nlo > lo));                               \
    hi = tk ? nhi : hi;                                                              \
    lo = tk ? nlo : lo; }

__global__ __launch_bounds__(256)
__attribute__((amdgpu_waves_per_eu(1, 1)))   // only 4 waves exist anyway; max reg budget
void fps_kernel(const float* __restrict__ p, float* __restrict__ p1,
                float* __restrict__ stats) {
#pragma clang fp contract(off)
  const int b = blockIdx.x;
  const int tid = threadIdx.x;
  if (tid < 96) stats[b*96 + tid] = 0.f;       // fused init: 4 blocks x 96 = 384 floats
  const float* pb = p + (size_t)b * (N_*3);
  float* p1b = p1 + (size_t)b * (M_*3);
  // SoA quads: plane[g*256+t] holds coord of points (t*32 + g*4 + 0..3).
  // Lane stride 16 B -> ds_read_b128 streaming. 96 KB total.
  __shared__ float4 xq[8*256];
  __shared__ float4 yq[8*256];
  __shared__ float4 zq[8*256];
  __shared__ ull slots[2][4];
  const int wv = tid >> 6;
  float d[32];
#pragma unroll
  for (int j = 0; j < 32; ++j) d[j] = 1e10f;
#pragma unroll
  for (int g = 0; g < 8; ++g) {
    const float* src = pb + (size_t)(tid*32 + g*4)*3;
    float4 a = ((const float4*)src)[0];    // x0 y0 z0 x1
    float4 c = ((const float4*)src)[1];    // y1 z1 x2 y2
    float4 e = ((const float4*)src)[2];    // z2 x3 y3 z3
    xq[g*256+tid] = make_float4(a.x, a.w, c.z, e.y);
    yq[g*256+tid] = make_float4(a.y, c.x, c.w, e.z);
    zq[g*256+tid] = make_float4(a.z, c.y, e.x, e.w);
  }
  float qx = pb[0], qy = pb[1], qz = pb[2];   // idx0 = 0
  if (tid == 0) { p1b[0] = qx; p1b[1] = qy; p1b[2] = qz; }
  __syncthreads();
  const float* xf = (const float*)xq;
  const float* yf = (const float*)yq;
  const float* zf = (const float*)zq;
  for (int t = 1; t < M_; ++t) {
    float tmax = -1.0f;
    int kbest = 0;
#pragma unroll
    for (int g = 0; g < 8; ++g) {
      float4 fx = xq[g*256+tid];
      float4 fy = yq[g*256+tid];
      float4 fz = zq[g*256+tid];
#pragma unroll
      for (int r = 0; r < 4; ++r) {
        int j = g*4 + r;
        float px = (r==0)?fx.x:((r==1)?fx.y:((r==2)?fx.z:fx.w));
        float py = (r==0)?fy.x:((r==1)?fy.y:((r==2)?fy.z:fy.w));
        float pz = (r==0)?fz.x:((r==1)?fz.y:((r==2)?fz.z:fz.w));
        // plain ops (contract off): matches XLA sub->square->seq-reduce exactly
        float dx = px - qx;
        float dy = py - qy;
        float dz = pz - qz;
        float s = (dx*dx + dy*dy) + dz*dz;
        float dj = fminf(d[j], s);
        d[j] = dj;
        bool c = dj > tmax;        // strict: first-index on local ties
        tmax = c ? dj : tmax;
        kbest = c ? j : kbest;
      }
    }
    unsigned int hi = __float_as_uint(tmax);
    unsigned int lo = ~(unsigned int)(tid*32 + kbest);
    // wave max-reduce of (hi,lo), result in lane 63
    DPPSTEP(0x111)  // row_shr:1
    DPPSTEP(0x112)  // row_shr:2
    DPPSTEP(0x114)  // row_shr:4
    DPPSTEP(0x118)  // row_shr:8
    DPPSTEP(0x142)  // row_bcast:15
    DPPSTEP(0x143)  // row_bcast:31
    if ((tid & 63) == 63) slots[t & 1][wv] = ((ull)hi << 32) | lo;
    __syncthreads();
    ull s0 = slots[t & 1][0], s1 = slots[t & 1][1];
    ull s2 = slots[t & 1][2], s3 = slots[t & 1][3];
    ull b0 = (s1 > s0) ? s1 : s0;
    ull b1 = (s3 > s2) ? s3 : s2;
    ull best = (b1 > b0) ? b1 : b0;
    int sel = (int)(~(unsigned int)best);
    sel = __builtin_amdgcn_readfirstlane(sel);
    // q fetch: 3 broadcast ds_read_b32 from the SoA planes
    int tq = sel >> 5, rem = sel & 31;
    int qoff = (((rem >> 2)*256 + tq) << 2) + (rem & 3);
    qx = xf[qoff]; qy = yf[qoff]; qz = zf[qoff];
    if (tid == 0) { p1b[t*3+0] = qx; p1b[t*3+1] = qy; p1b[t*3+2] = qz; }
  }
}

// ---------- kNN + gather + fused stats1: 8 queries/block, 32 threads/query ----------
#define TILE_ 1024
__global__ __launch_bounds__(256) void knn_kernel(const float* __restrict__ p,
                                                  const float* __restrict__ p1,
                                                  const float* __restrict__ W1,
                                                  float* __restrict__ gfp,
                                                  float* __restrict__ stats) {
  const int blk = blockIdx.x;       // 1024 blocks = 4 batches x 256
  const int b = blk >> 8;
  const int q0 = (blk & 255) * 8;
  __shared__ float4 tile[TILE_];    // 16 KB (reused as lgf/bs scratch in epilogue)
  __shared__ ull mk[8*32*20];       // 40 KB
  const int tid = threadIdx.x;
  const int ql = tid >> 5;          // 0..7 query within block
  const int part = tid & 31;        // 0..31 part
  const int m = q0 + ql;
  const float* pb = p + (size_t)b*(N_*3);
  const float* qp_ = p1 + ((size_t)b*M_ + m)*3;
  float qx = qp_[0], qy = qp_[1], qz = qp_[2];
  float qq = __fadd_rn(__fadd_rn(__fmul_rn(qx,qx), __fmul_rn(qy,qy)), __fmul_rn(qz,qz));
  ull keys[20];
#pragma unroll
  for (int i = 0; i < 20; ++i) keys[i] = 0xFF8000007FFFFFFFull;  // pack(+inf, INT_MAX)
  float maxf = __uint_as_float(0x7F800000u);  // +inf
  for (int t0 = 0; t0 < N_; t0 += TILE_) {
    __syncthreads();
    for (int i = tid; i < TILE_; i += 256) {
      float x = pb[(t0+i)*3+0], y = pb[(t0+i)*3+1], z = pb[(t0+i)*3+2];
      float pp = __fadd_rn(__fadd_rn(__fmul_rn(x,x), __fmul_rn(y,y)), __fmul_rn(z,z));
      tile[i] = make_float4(x, y, z, pp);
    }
    __syncthreads();
    const int sbase = part * 32;
    for (int s = 0; s < 32; ++s) {
      int ss = sbase + ((s + part) & 31);       // bank skew across parts
      float4 pt = tile[ss];
      // d = (qq+pp) - 2*qp with qp as fmuladd chain (matches XLA dot emitter)
      float qp = fmaf(pt.z, qz, fmaf(pt.y, qy, __fmul_rn(pt.x, qx)));
      float d = __fsub_rn(__fadd_rn(qq, pt.w), __fmul_rn(2.0f, qp));
      if (d <= maxf) {
        ull key = packkey(d, t0 + ss);
        if (key < keys[19]) { insert20(keys, key); maxf = keymaxf(keys[19]); }
      }
    }
  }
  ull* myslot = &mk[(ql*32 + part)*20];
#pragma unroll
  for (int i = 0; i < 20; ++i) myslot[i] = keys[i];
  __syncthreads();
  if (part == 0) {       // leader merges 32x20 sorted lists
    for (int pp2 = 1; pp2 < 32; ++pp2) {
      const ull* os = &mk[(ql*32 + pp2)*20];
      for (int i = 0; i < 20; ++i) {
        ull k = os[i];
        if (k >= keys[19]) break;    // sorted -> rest can't enter
        insert20(keys, k);
      }
    }
#pragma unroll
    for (int i = 0; i < 20; ++i) myslot[i] = keys[i];
  }
  __syncthreads();
  // epilogue scratch in spent tile LDS: lgf[960] gf values, bsf[128] block sums
  float* lgf = (float*)tile;
  float* bsf = ((float*)tile) + 960;
  if (tid < 128) bsf[tid] = 0.f;
  // write gf planes [6][B*M*K] + stash gf in LDS for fused stats1
  for (int w = tid; w < 8*K_; w += 256) {
    int ql2 = w / K_;
    int kk = w - ql2*K_;
    ull key = mk[ql2*32*20 + kk];
    int idx = (int)(unsigned int)(key & 0xFFFFFFFFu);
    float gx = pb[idx*3+0], gy = pb[idx*3+1], gz = pb[idx*3+2];
    int m2 = q0 + ql2;
    const float* qv = p1 + ((size_t)b*M_ + m2)*3;
    size_t col = ((size_t)(b*M_ + m2))*K_ + kk;
    float dx = __fsub_rn(gx, qv[0]);
    float dy = __fsub_rn(gy, qv[1]);
    float dz = __fsub_rn(gz, qv[2]);
    gfp[0*BMK + col] = dx;
    gfp[1*BMK + col] = dy;
    gfp[2*BMK + col] = dz;
    gfp[3*BMK + col] = gx;
    gfp[4*BMK + col] = gy;
    gfp[5*BMK + col] = gz;
    float* lg = lgf + w*6;
    lg[0] = dx; lg[1] = dy; lg[2] = dz; lg[3] = gx; lg[4] = gy; lg[5] = gz;
  }
  __syncthreads();
  // fused stats1: lane=channel, each of 4 waves scans 40 of the block's 160 cols
  const int lane = tid & 63;
  const int wv2 = tid >> 6;
  float w1r[6];
#pragma unroll
  for (int c = 0; c < 6; ++c) w1r[c] = W1[lane*6 + c];
  float acc = 0.f, accq = 0.f;
  for (int cc = wv2*40; cc < wv2*40 + 40; ++cc) {
    const float* lg = lgf + cc*6;
    float yv = __fmul_rn(w1r[0], lg[0]);
#pragma unroll
    for (int c = 1; c < 6; ++c) yv = fmaf(w1r[c], lg[c], yv);
    float u = (yv >= 0.f) ? yv : 0.2f*yv;
    acc += u;
    accq = fmaf(u, u, accq);
  }
  atomicAdd(&bsf[lane], acc);
  atomicAdd(&bsf[64+lane], accq);
  __syncthreads();
  if (tid < 128) atomicAdd(&stats[tid], bsf[tid]);
}

// BN coefficient replication (bit-identical to the old finalize_kernel)
__device__ __forceinline__ void bn_coeff(const float* __restrict__ st,
                                         const float* __restrict__ g,
                                         const float* __restrict__ bb,
                                         int o, float& A, float& C) {
  const float inv = 1.0f / (float)BMK;
  float mean = st[o] * inv;
  float var  = st[64+o] * inv - mean*mean;
  float a = g[o] / sqrtf(var + EPS_);
  A = a;
  C = fmaf(-a, mean, bb[o]);
}

// ---------- pass B (+finalize1 +fused stats2): gf -> x1 -> conv2 -> lrelu -> u2t ----------
#define TSTRIDE 68   // padded LDS stride (floats), 16B-aligned, breaks pow2 banking
__global__ __launch_bounds__(256) void convB_kernel(const float* __restrict__ gfp,
                                                    const float* __restrict__ W1,
                                                    const float* __restrict__ stats,  // layer-1 sums
                                                    const float* __restrict__ g1,
                                                    const float* __restrict__ b1,
                                                    const float* __restrict__ W2,
                                                    float* __restrict__ u2t,
                                                    float* __restrict__ stats2o) {
  __shared__ float sA[64], sC[64];
  __shared__ float lds_t[256*TSTRIDE];   // 68 KB u2 tile for stats transpose
  __shared__ float bs[128];
  const int tid = threadIdx.x;
  if (tid < 64) bn_coeff(stats, g1, b1, tid, sA[tid], sC[tid]);
  if (tid < 128) bs[tid] = 0.f;
  __syncthreads();
  const int col = blockIdx.x * 256 + tid;           // 640*256 = 163840 exact
  float gf[6];
#pragma unroll
  for (int c = 0; c < 6; ++c) gf[c] = gfp[c*BMK + col];
  float x1[64];
#pragma unroll
  for (int c = 0; c < 64; ++c) {
    float y = __fmul_rn(W1[c*6+0], gf[0]);
#pragma unroll
    for (int i = 1; i < 6; ++i) y = fmaf(W1[c*6+i], gf[i], y);
    float u = (y >= 0.f) ? y : 0.2f*y;
    x1[c] = fmaf(sA[c], u, sC[c]);
  }
  float* ob = u2t + (size_t)col * 64;
  float* myrow = lds_t + tid*TSTRIDE;
  for (int o4 = 0; o4 < 16; ++o4) {
    float y0 = 0.f, y1 = 0.f, y2 = 0.f, y3 = 0.f;
#pragma unroll
    for (int c = 0; c < 64; ++c) {
      float xc = x1[c];
      y0 = fmaf(W2[(o4*4+0)*64+c], xc, y0);
      y1 = fmaf(W2[(o4*4+1)*64+c], xc, y1);
      y2 = fmaf(W2[(o4*4+2)*64+c], xc, y2);
      y3 = fmaf(W2[(o4*4+3)*64+c], xc, y3);
    }
    float4 v;
    v.x = (y0 >= 0.f) ? y0 : 0.2f*y0;
    v.y = (y1 >= 0.f) ? y1 : 0.2f*y1;
    v.z = (y2 >= 0.f) ? y2 : 0.2f*y2;
    v.w = (y3 >= 0.f) ? y3 : 0.2f*y3;
    ((float4*)ob)[o4] = v;
    *((float4*)(myrow + o4*4)) = v;
  }
  __syncthreads();
  // fused stats2: thread (c = tid&63, grp = tid>>6) sums channel c over 64 cols
  const int c = tid & 63;
  const int grp = tid >> 6;
  float acc = 0.f, accq = 0.f;
  for (int i = 0; i < 64; ++i) {
    float u = lds_t[(grp*64 + i)*TSTRIDE + c];
    acc += u;
    accq = fmaf(u, u, accq);
  }
  atomicAdd(&bs[c], acc);
  atomicAdd(&bs[64+c], accq);
  __syncthreads();
  if (tid < 128) atomicAdd(&stats2o[tid], bs[tid]);
}

// ---------- pool3 (stats3 + maxpool, single u2t pass): per (b,m) wave x4 ----------
__global__ __launch_bounds__(256) void pool3_kernel(const float* __restrict__ u2t,
                                                    const float* __restrict__ W3,
                                                    const float* __restrict__ stats2v,
                                                    const float* __restrict__ g2,
                                                    const float* __restrict__ b2,
                                                    float* __restrict__ stats,
                                                    float* __restrict__ mxmn) {
  __shared__ float sA2[64], sC2[64];
  __shared__ float bs[128];
  const int tid = threadIdx.x;
  if (tid < 64) bn_coeff(stats2v, g2, b2, tid, sA2[tid], sC2[tid]);
  if (tid < 128) bs[tid] = 0.f;
  __syncthreads();
  const int lane = tid & 63;
  float w[64];
#pragma unroll
  for (int c = 0; c < 64; ++c) w[c] = W3[lane*64 + c] * sA2[c];   // == W3f
  float bb = 0.f;
#pragma unroll
  for (int c = 0; c < 64; ++c) bb = fmaf(W3[lane*64 + c], sC2[c], bb);  // == b3f
  const int wg = (blockIdx.x*256 + tid) >> 6;   // 0..2047
  float acc = 0.f, accq = 0.f;
  for (int rep = 0; rep < 4; ++rep) {
    const int wv = wg*4 + rep;                  // 0..8191 = b*M + m
    float mx = -3.4e38f, mn = 3.4e38f;
    for (int k = 0; k < K_; ++k) {
      const float4* u4 = (const float4*)(u2t + ((size_t)wv*K_ + k)*64);
      float y = bb;
#pragma unroll
      for (int c4 = 0; c4 < 16; ++c4) {
        float4 v = u4[c4];
        y = fmaf(w[4*c4+0], v.x, y);
        y = fmaf(w[4*c4+1], v.y, y);
        y = fmaf(w[4*c4+2], v.z, y);
        y = fmaf(w[4*c4+3], v.w, y);
      }
      float u = (y >= 0.f) ? y : 0.2f*y;
      acc += u; accq = fmaf(u, u, accq);
      mx = fmaxf(mx, u); mn = fminf(mn, u);
    }
    mxmn[(size_t)wv*128 + lane] = mx;
    mxmn[(size_t)wv*128 + 64 + lane] = mn;
  }
  atomicAdd(&bs[lane], acc);
  atomicAdd(&bs[64+lane], accq);
  __syncthreads();
  if (tid < 128) atomicAdd(&stats[tid], bs[tid]);
}

// ---------- apply (finalize3): r = A3>=0 ? mx : mn; out = A3*r + C3 ----------
__global__ __launch_bounds__(256) void apply_kernel(const float* __restrict__ stats3v,
                                                    const float* __restrict__ g3,
                                                    const float* __restrict__ b3,
                                                    const float* __restrict__ mxmn,
                                                    float* __restrict__ out) {
  const int tid = threadIdx.x;
  const int lane = tid & 63;
  float A3, C3;
  bn_coeff(stats3v, g3, b3, lane, A3, C3);
  const int wg = (blockIdx.x*256 + tid) >> 6;   // 0..2047
  for (int rep = 0; rep < 4; ++rep) {
    const int wv = wg*4 + rep;
    float mx = mxmn[(size_t)wv*128 + lane];
    float mn = mxmn[(size_t)wv*128 + 64 + lane];
    float r = (A3 >= 0.f) ? mx : mn;   // affine commutes with max when a>=0
    int b = wv >> 11, m = wv & 2047;
    out[((size_t)(b*64 + lane))*M_ + m] = fmaf(A3, r, C3);
  }
}

// ---------- launch ----------
extern "C" void kernel_launch(void* const* d_in, const int* in_sizes, int n_in,
                              void* d_out, int out_size, void* d_ws, size_t ws_size,
                              hipStream_t stream) {
  const float* p  = (const float*)d_in[0];
  const float* W1 = (const float*)d_in[1];
  const float* g1 = (const float*)d_in[2];
  const float* b1 = (const float*)d_in[3];
  const float* W2 = (const float*)d_in[4];
  const float* g2 = (const float*)d_in[5];
  const float* b2 = (const float*)d_in[6];
  const float* W3 = (const float*)d_in[7];
  const float* g3 = (const float*)d_in[8];
  const float* b3 = (const float*)d_in[9];
  float* out = (float*)d_out;
  char* ws = (char*)d_ws;

  // workspace layout (46.2 MB total; mxmn reuses the dead p1/gfp region)
  float* p1    = (float*)(ws);                 // 98,304 B   (dead after convB)
  float* gfp   = (float*)(ws + 131072);        // 3,932,160 B (dead after convB)
  float* mxmn  = (float*)(ws);                 // 4,194,304 B (alias: live from pool3 on)
  float* u2t   = (float*)(ws + 4194304);       // 41,943,040 B
  float* stats = (float*)(ws + 46137344);      // 384 f (sum/sq x3 layers)

  hipLaunchKernelGGL(fps_kernel,   dim3(4),    dim3(256), 0, stream, p, p1, stats);
  hipLaunchKernelGGL(knn_kernel,   dim3(1024), dim3(256), 0, stream, p, p1, W1, gfp, stats);
  hipLaunchKernelGGL(convB_kernel, dim3(640),  dim3(256), 0, stream, gfp, W1, stats, g1, b1, W2, u2t, stats+128);
  hipLaunchKernelGGL(pool3_kernel, dim3(512),  dim3(256), 0, stream, u2t, W3, stats+128, g2, b2, stats+256, mxmn);
  hipLaunchKernelGGL(apply_kernel, dim3(512),  dim3(256), 0, stream, stats+256, g3, b3, mxmn, out);
}

// Round 11
// 3273.989 us; speedup vs baseline: 1.0736x; 1.0736x over previous
//
#include <hip/hip_runtime.h>
#include <cstdint>
#include <cstddef>

// GroupPointNet: FPS -> kNN(20) -> gf=(dp,grouped) -> 3x(conv1x1+lrelu+BN) -> max_k
// B=4, N=8192, M=2048, K=20, C=64. All f32.
// R11: fps = R6 winner (256thr x 32pts scalar regs, wpe(1,1)) + 4-way split argmax
// chains (cuts 32-deep dependent cmp chain to 8-deep). Pipeline = R10 (5 launches).

#define B_ 4
#define N_ 8192
#define M_ 2048
#define K_ 20
#define BMK (B_*M_*K_)   // 163840
#define EPS_ 1e-5f

typedef unsigned long long ull;

// ---------- helpers ----------
__device__ __forceinline__ ull packkey(float d, int idx) {
  unsigned int bb = __float_as_uint(d);
  bb ^= (bb & 0x80000000u) ? 0xFFFFFFFFu : 0x80000000u;  // order-preserving map
  return ((ull)bb << 32) | (unsigned int)idx;
}
__device__ __forceinline__ float keymaxf(ull k) {
  unsigned int hb = (unsigned int)(k >> 32);
  unsigned int fb = (hb & 0x80000000u) ? (hb ^ 0x80000000u) : ~hb;
  return __uint_as_float(fb);
}
// keys sorted ascending; caller guarantees key < keys[19]
__device__ __forceinline__ void insert20(ull* keys, ull key) {
#pragma unroll
  for (int i = 19; i > 0; --i) {
    ull lo = keys[i-1];
    keys[i] = (key < lo) ? lo : ((key < keys[i]) ? key : keys[i]);
  }
  keys[0] = (key < keys[0]) ? key : keys[0];
}

// ---------- FPS: 1 block/batch, 256 thr x 32 pts SCALAR regs, split-4 argmax ----------
// key = (dist_bits << 32) | ~idx : max-reduce => argmax with first-index tie-break.
// dist >= 0 so float bits compare as u32. Also zeros the stats accumulators (init fused).
#define DPPSTEP(CTRL) {                                                              \
    unsigned int nhi = (unsigned int)__builtin_amdgcn_update_dpp(                    \
        (int)hi, (int)hi, CTRL, 0xF, 0xF, false);                                    \
    unsigned int nlo = (unsigned int)__builtin_amdgcn_update_dpp(                    \
        (int)lo, (int)lo, CTRL, 0xF, 0xF, false);                                    \
    bool tk = (nhi > hi) | ((nhi == hi) & (nlo > lo));                               \
    hi = tk ? nhi : hi;                                                              \
    lo = tk ? nlo : lo; }

// one split-chain step: chain state (tm, kb), candidate (dj, j)
#define CHAINSTEP(J, TM, KB) {                                                       \
    float dx = x[J] - qx;                                                            \
    float dy = y[J] - qy;                                                            \
    float dz = z[J] - qz;                                                            \
    float s = (dx*dx + dy*dy) + dz*dz;                                               \
    float dj = fminf(d[J], s);                                                       \
    d[J] = dj;                                                                       \
    bool c = dj > TM;                                                                \
    TM = c ? dj : TM;                                                                \
    KB = c ? (J) : KB; }

__global__ __launch_bounds__(256)
__attribute__((amdgpu_waves_per_eu(1, 1)))   // 1 wave/SIMD: max reg budget (R6 winner)
void fps_kernel(const float* __restrict__ p, float* __restrict__ p1,
                float* __restrict__ stats) {
#pragma clang fp contract(off)
  const int b = blockIdx.x;
  const int tid = threadIdx.x;
  if (tid < 96) stats[b*96 + tid] = 0.f;       // fused init: 4 blocks x 96 = 384 floats
  const float* pb = p + (size_t)b * (N_*3);
  float* p1b = p1 + (size_t)b * (M_*3);
  __shared__ float4 pts4[N_];      // 128 KB: broadcast q-fetch off the critical path
  __shared__ ull slots[2][4];
  const int wv = tid >> 6;
  const int base = tid * 32;       // 32 points per thread, scalar registers
  float x[32], y[32], z[32], d[32];
#pragma unroll
  for (int j = 0; j < 32; ++j) {
    int i = base + j;
    float xx = pb[i*3+0], yy = pb[i*3+1], zz = pb[i*3+2];
    x[j] = xx; y[j] = yy; z[j] = zz;
    d[j] = 1e10f;
    pts4[i] = make_float4(xx, yy, zz, 0.f);
  }
  float qx = pb[0], qy = pb[1], qz = pb[2];   // idx0 = 0
  if (tid == 0) { p1b[0] = qx; p1b[1] = qy; p1b[2] = qz; }
  __syncthreads();
  for (int t = 1; t < M_; ++t) {
    // 4 independent argmax chains (indices j%4==c), each 8-deep -> 4x less dep latency
    float t0 = -1.f, t1 = -1.f, t2 = -1.f, t3 = -1.f;
    int k0 = 0, k1 = 0, k2 = 0, k3 = 0;
#pragma unroll
    for (int j4 = 0; j4 < 8; ++j4) {
      CHAINSTEP(4*j4+0, t0, k0)
      CHAINSTEP(4*j4+1, t1, k1)
      CHAINSTEP(4*j4+2, t2, k2)
      CHAINSTEP(4*j4+3, t3, k3)
    }
    // merge with first-index tie-break (smaller j wins on equal dist)
    bool s1 = (t1 > t0) || ((t1 == t0) && (k1 < k0));
    float ta = s1 ? t1 : t0; int ka = s1 ? k1 : k0;
    bool s2 = (t3 > t2) || ((t3 == t2) && (k3 < k2));
    float tb = s2 ? t3 : t2; int kb = s2 ? k3 : k2;
    bool s3 = (tb > ta) || ((tb == ta) && (kb < ka));
    float tmax = s3 ? tb : ta;
    int kbest = s3 ? kb : ka;
    unsigned int hi = __float_as_uint(tmax);
    unsigned int lo = ~(unsigned int)(base + kbest);
    // wave max-reduce of (hi,lo), result in lane 63
    DPPSTEP(0x111)  // row_shr:1
    DPPSTEP(0x112)  // row_shr:2
    DPPSTEP(0x114)  // row_shr:4
    DPPSTEP(0x118)  // row_shr:8
    DPPSTEP(0x142)  // row_bcast:15
    DPPSTEP(0x143)  // row_bcast:31
    if ((tid & 63) == 63) slots[t & 1][wv] = ((ull)hi << 32) | lo;
    __syncthreads();
    ull s0 = slots[t & 1][0], sl1 = slots[t & 1][1];
    ull sl2 = slots[t & 1][2], sl3 = slots[t & 1][3];
    ull b0 = (sl1 > s0) ? sl1 : s0;
    ull b1 = (sl3 > sl2) ? sl3 : sl2;
    ull best = (b1 > b0) ? b1 : b0;
    int sel = (int)(~(unsigned int)best);
    sel = __builtin_amdgcn_readfirstlane(sel);
    float4 qv = pts4[sel];          // broadcast ds_read_b128
    qx = qv.x; qy = qv.y; qz = qv.z;
    if (tid == 0) { p1b[t*3+0] = qx; p1b[t*3+1] = qy; p1b[t*3+2] = qz; }
  }
}

// ---------- kNN + gather + fused stats1: 8 queries/block, 32 threads/query ----------
#define TILE_ 1024
__global__ __launch_bounds__(256) void knn_kernel(const float* __restrict__ p,
                                                  const float* __restrict__ p1,
                                                  const float* __restrict__ W1,
                                                  float* __restrict__ gfp,
                                                  float* __restrict__ stats) {
  const int blk = blockIdx.x;       // 1024 blocks = 4 batches x 256
  const int b = blk >> 8;
  const int q0 = (blk & 255) * 8;
  __shared__ float4 tile[TILE_];    // 16 KB (reused as lgf/bs scratch in epilogue)
  __shared__ ull mk[8*32*20];       // 40 KB
  const int tid = threadIdx.x;
  const int ql = tid >> 5;          // 0..7 query within block
  const int part = tid & 31;        // 0..31 part
  const int m = q0 + ql;
  const float* pb = p + (size_t)b*(N_*3);
  const float* qp_ = p1 + ((size_t)b*M_ + m)*3;
  float qx = qp_[0], qy = qp_[1], qz = qp_[2];
  float qq = __fadd_rn(__fadd_rn(__fmul_rn(qx,qx), __fmul_rn(qy,qy)), __fmul_rn(qz,qz));
  ull keys[20];
#pragma unroll
  for (int i = 0; i < 20; ++i) keys[i] = 0xFF8000007FFFFFFFull;  // pack(+inf, INT_MAX)
  float maxf = __uint_as_float(0x7F800000u);  // +inf
  for (int t0 = 0; t0 < N_; t0 += TILE_) {
    __syncthreads();
    for (int i = tid; i < TILE_; i += 256) {
      float x = pb[(t0+i)*3+0], y = pb[(t0+i)*3+1], z = pb[(t0+i)*3+2];
      float pp = __fadd_rn(__fadd_rn(__fmul_rn(x,x), __fmul_rn(y,y)), __fmul_rn(z,z));
      tile[i] = make_float4(x, y, z, pp);
    }
    __syncthreads();
    const int sbase = part * 32;
    for (int s = 0; s < 32; ++s) {
      int ss = sbase + ((s + part) & 31);       // bank skew across parts
      float4 pt = tile[ss];
      // d = (qq+pp) - 2*qp with qp as fmuladd chain (matches XLA dot emitter)
      float qp = fmaf(pt.z, qz, fmaf(pt.y, qy, __fmul_rn(pt.x, qx)));
      float d = __fsub_rn(__fadd_rn(qq, pt.w), __fmul_rn(2.0f, qp));
      if (d <= maxf) {
        ull key = packkey(d, t0 + ss);
        if (key < keys[19]) { insert20(keys, key); maxf = keymaxf(keys[19]); }
      }
    }
  }
  ull* myslot = &mk[(ql*32 + part)*20];
#pragma unroll
  for (int i = 0; i < 20; ++i) myslot[i] = keys[i];
  __syncthreads();
  if (part == 0) {       // leader merges 32x20 sorted lists
    for (int pp2 = 1; pp2 < 32; ++pp2) {
      const ull* os = &mk[(ql*32 + pp2)*20];
      for (int i = 0; i < 20; ++i) {
        ull k = os[i];
        if (k >= keys[19]) break;    // sorted -> rest can't enter
        insert20(keys, k);
      }
    }
#pragma unroll
    for (int i = 0; i < 20; ++i) myslot[i] = keys[i];
  }
  __syncthreads();
  // epilogue scratch in spent tile LDS: lgf[960] gf values, bsf[128] block sums
  float* lgf = (float*)tile;
  float* bsf = ((float*)tile) + 960;
  if (tid < 128) bsf[tid] = 0.f;
  // write gf planes [6][B*M*K] + stash gf in LDS for fused stats1
  for (int w = tid; w < 8*K_; w += 256) {
    int ql2 = w / K_;
    int kk = w - ql2*K_;
    ull key = mk[ql2*32*20 + kk];
    int idx = (int)(unsigned int)(key & 0xFFFFFFFFu);
    float gx = pb[idx*3+0], gy = pb[idx*3+1], gz = pb[idx*3+2];
    int m2 = q0 + ql2;
    const float* qv = p1 + ((size_t)b*M_ + m2)*3;
    size_t col = ((size_t)(b*M_ + m2))*K_ + kk;
    float dx = __fsub_rn(gx, qv[0]);
    float dy = __fsub_rn(gy, qv[1]);
    float dz = __fsub_rn(gz, qv[2]);
    gfp[0*BMK + col] = dx;
    gfp[1*BMK + col] = dy;
    gfp[2*BMK + col] = dz;
    gfp[3*BMK + col] = gx;
    gfp[4*BMK + col] = gy;
    gfp[5*BMK + col] = gz;
    float* lg = lgf + w*6;
    lg[0] = dx; lg[1] = dy; lg[2] = dz; lg[3] = gx; lg[4] = gy; lg[5] = gz;
  }
  __syncthreads();
  // fused stats1: lane=channel, each of 4 waves scans 40 of the block's 160 cols
  const int lane = tid & 63;
  const int wv2 = tid >> 6;
  float w1r[6];
#pragma unroll
  for (int c = 0; c < 6; ++c) w1r[c] = W1[lane*6 + c];
  float acc = 0.f, accq = 0.f;
  for (int cc = wv2*40; cc < wv2*40 + 40; ++cc) {
    const float* lg = lgf + cc*6;
    float yv = __fmul_rn(w1r[0], lg[0]);
#pragma unroll
    for (int c = 1; c < 6; ++c) yv = fmaf(w1r[c], lg[c], yv);
    float u = (yv >= 0.f) ? yv : 0.2f*yv;
    acc += u;
    accq = fmaf(u, u, accq);
  }
  atomicAdd(&bsf[lane], acc);
  atomicAdd(&bsf[64+lane], accq);
  __syncthreads();
  if (tid < 128) atomicAdd(&stats[tid], bsf[tid]);
}

// BN coefficient replication (bit-identical to the old finalize_kernel)
__device__ __forceinline__ void bn_coeff(const float* __restrict__ st,
                                         const float* __restrict__ g,
                                         const float* __restrict__ bb,
                                         int o, float& A, float& C) {
  const float inv = 1.0f / (float)BMK;
  float mean = st[o] * inv;
  float var  = st[64+o] * inv - mean*mean;
  float a = g[o] / sqrtf(var + EPS_);
  A = a;
  C = fmaf(-a, mean, bb[o]);
}

// ---------- pass B (+finalize1 +fused stats2): gf -> x1 -> conv2 -> lrelu -> u2t ----------
#define TSTRIDE 68   // padded LDS stride (floats), 16B-aligned, breaks pow2 banking
__global__ __launch_bounds__(256) void convB_kernel(const float* __restrict__ gfp,
                                                    const float* __restrict__ W1,
                                                    const float* __restrict__ stats,  // layer-1 sums
                                                    const float* __restrict__ g1,
                                                    const float* __restrict__ b1,
                                                    const float* __restrict__ W2,
                                                    float* __restrict__ u2t,
                                                    float* __restrict__ stats2o) {
  __shared__ float sA[64], sC[64];
  __shared__ float lds_t[256*TSTRIDE];   // 68 KB u2 tile for stats transpose
  __shared__ float bs[128];
  const int tid = threadIdx.x;
  if (tid < 64) bn_coeff(stats, g1, b1, tid, sA[tid], sC[tid]);
  if (tid < 128) bs[tid] = 0.f;
  __syncthreads();
  const int col = blockIdx.x * 256 + tid;           // 640*256 = 163840 exact
  float gf[6];
#pragma unroll
  for (int c = 0; c < 6; ++c) gf[c] = gfp[c*BMK + col];
  float x1[64];
#pragma unroll
  for (int c = 0; c < 64; ++c) {
    float y = __fmul_rn(W1[c*6+0], gf[0]);
#pragma unroll
    for (int i = 1; i < 6; ++i) y = fmaf(W1[c*6+i], gf[i], y);
    float u = (y >= 0.f) ? y : 0.2f*y;
    x1[c] = fmaf(sA[c], u, sC[c]);
  }
  float* ob = u2t + (size_t)col * 64;
  float* myrow = lds_t + tid*TSTRIDE;
  for (int o4 = 0; o4 < 16; ++o4) {
    float y0 = 0.f, y1 = 0.f, y2 = 0.f, y3 = 0.f;
#pragma unroll
    for (int c = 0; c < 64; ++c) {
      float xc = x1[c];
      y0 = fmaf(W2[(o4*4+0)*64+c], xc, y0);
      y1 = fmaf(W2[(o4*4+1)*64+c], xc, y1);
      y2 = fmaf(W2[(o4*4+2)*64+c], xc, y2);
      y3 = fmaf(W2[(o4*4+3)*64+c], xc, y3);
    }
    float4 v;
    v.x = (y0 >= 0.f) ? y0 : 0.2f*y0;
    v.y = (y1 >= 0.f) ? y1 : 0.2f*y1;
    v.z = (y2 >= 0.f) ? y2 : 0.2f*y2;
    v.w = (y3 >= 0.f) ? y3 : 0.2f*y3;
    ((float4*)ob)[o4] = v;
    *((float4*)(myrow + o4*4)) = v;
  }
  __syncthreads();
  // fused stats2: thread (c = tid&63, grp = tid>>6) sums channel c over 64 cols
  const int c = tid & 63;
  const int grp = tid >> 6;
  float acc = 0.f, accq = 0.f;
  for (int i = 0; i < 64; ++i) {
    float u = lds_t[(grp*64 + i)*TSTRIDE + c];
    acc += u;
    accq = fmaf(u, u, accq);
  }
  atomicAdd(&bs[c], acc);
  atomicAdd(&bs[64+c], accq);
  __syncthreads();
  if (tid < 128) atomicAdd(&stats2o[tid], bs[tid]);
}

// ---------- pool3 (stats3 + maxpool, single u2t pass): per (b,m) wave x4 ----------
__global__ __launch_bounds__(256) void pool3_kernel(const float* __restrict__ u2t,
                                                    const float* __restrict__ W3,
                                                    const float* __restrict__ stats2v,
                                                    const float* __restrict__ g2,
                                                    const float* __restrict__ b2,
                                                    float* __restrict__ stats,
                                                    float* __restrict__ mxmn) {
  __shared__ float sA2[64], sC2[64];
  __shared__ float bs[128];
  const int tid = threadIdx.x;
  if (tid < 64) bn_coeff(stats2v, g2, b2, tid, sA2[tid], sC2[tid]);
  if (tid < 128) bs[tid] = 0.f;
  __syncthreads();
  const int lane = tid & 63;
  float w[64];
#pragma unroll
  for (int c = 0; c < 64; ++c) w[c] = W3[lane*64 + c] * sA2[c];   // == W3f
  float bb = 0.f;
#pragma unroll
  for (int c = 0; c < 64; ++c) bb = fmaf(W3[lane*64 + c], sC2[c], bb);  // == b3f
  const int wg = (blockIdx.x*256 + tid) >> 6;   // 0..2047
  float acc = 0.f, accq = 0.f;
  for (int rep = 0; rep < 4; ++rep) {
    const int wv = wg*4 + rep;                  // 0..8191 = b*M + m
    float mx = -3.4e38f, mn = 3.4e38f;
    for (int k = 0; k < K_; ++k) {
      const float4* u4 = (const float4*)(u2t + ((size_t)wv*K_ + k)*64);
      float y = bb;
#pragma unroll
      for (int c4 = 0; c4 < 16; ++c4) {
        float4 v = u4[c4];
        y = fmaf(w[4*c4+0], v.x, y);
        y = fmaf(w[4*c4+1], v.y, y);
        y = fmaf(w[4*c4+2], v.z, y);
        y = fmaf(w[4*c4+3], v.w, y);
      }
      float u = (y >= 0.f) ? y : 0.2f*y;
      acc += u; accq = fmaf(u, u, accq);
      mx = fmaxf(mx, u); mn = fminf(mn, u);
    }
    mxmn[(size_t)wv*128 + lane] = mx;
    mxmn[(size_t)wv*128 + 64 + lane] = mn;
  }
  atomicAdd(&bs[lane], acc);
  atomicAdd(&bs[64+lane], accq);
  __syncthreads();
  if (tid < 128) atomicAdd(&stats[tid], bs[tid]);
}

// ---------- apply (finalize3): r = A3>=0 ? mx : mn; out = A3*r + C3 ----------
__global__ __launch_bounds__(256) void apply_kernel(const float* __restrict__ stats3v,
                                                    const float* __restrict__ g3,
                                                    const float* __restrict__ b3,
                                                    const float* __restrict__ mxmn,
                                                    float* __restrict__ out) {
  const int tid = threadIdx.x;
  const int lane = tid & 63;
  float A3, C3;
  bn_coeff(stats3v, g3, b3, lane, A3, C3);
  const int wg = (blockIdx.x*256 + tid) >> 6;   // 0..2047
  for (int rep = 0; rep < 4; ++rep) {
    const int wv = wg*4 + rep;
    float mx = mxmn[(size_t)wv*128 + lane];
    float mn = mxmn[(size_t)wv*128 + 64 + lane];
    float r = (A3 >= 0.f) ? mx : mn;   // affine commutes with max when a>=0
    int b = wv >> 11, m = wv & 2047;
    out[((size_t)(b*64 + lane))*M_ + m] = fmaf(A3, r, C3);
  }
}

// ---------- launch ----------
extern "C" void kernel_launch(void* const* d_in, const int* in_sizes, int n_in,
                              void* d_out, int out_size, void* d_ws, size_t ws_size,
                              hipStream_t stream) {
  const float* p  = (const float*)d_in[0];
  const float* W1 = (const float*)d_in[1];
  const float* g1 = (const float*)d_in[2];
  const float* b1 = (const float*)d_in[3];
  const float* W2 = (const float*)d_in[4];
  const float* g2 = (const float*)d_in[5];
  const float* b2 = (const float*)d_in[6];
  const float* W3 = (const float*)d_in[7];
  const float* g3 = (const float*)d_in[8];
  const float* b3 = (const float*)d_in[9];
  float* out = (float*)d_out;
  char* ws = (char*)d_ws;

  // workspace layout (46.2 MB total; mxmn reuses the dead p1/gfp region)
  float* p1    = (float*)(ws);                 // 98,304 B   (dead after convB)
  float* gfp   = (float*)(ws + 131072);        // 3,932,160 B (dead after convB)
  float* mxmn  = (float*)(ws);                 // 4,194,304 B (alias: live from pool3 on)
  float* u2t   = (float*)(ws + 4194304);       // 41,943,040 B
  float* stats = (float*)(ws + 46137344);      // 384 f (sum/sq x3 layers)

  hipLaunchKernelGGL(fps_kernel,   dim3(4),    dim3(256), 0, stream, p, p1, stats);
  hipLaunchKernelGGL(knn_kernel,   dim3(1024), dim3(256), 0, stream, p, p1, W1, gfp, stats);
  hipLaunchKernelGGL(convB_kernel, dim3(640),  dim3(256), 0, stream, gfp, W1, stats, g1, b1, W2, u2t, stats+128);
  hipLaunchKernelGGL(pool3_kernel, dim3(512),  dim3(256), 0, stream, u2t, W3, stats+128, g2, b2, stats+256, mxmn);
  hipLaunchKernelGGL(apply_kernel, dim3(512),  dim3(256), 0, stream, stats+256, g3, b3, mxmn, out);
}